// Round 11
// baseline (28.599 us; speedup 1.0000x reference)
//
#include <hip/hip_runtime.h>
#include <math.h>

#define HS 64
#define WS 208
#define HF 128
#define WF 416
#define NS (HS * WS)   // 13312
#define KH 20
#define KS 41
#define KK (KS * KS)   // 1681
#define TW 8           // tile width in pixels
#define TH 4           // tile height in pixels
#define NBX (WS / TW)  // 26
#define NBY (HS / TH)  // 16
#define NBLK (NBX * NBY) // 416
#define TROW 44        // union rows (4-1+41)
#define TCOL 48        // union cols (8-1+41)
#define PITCH 49       // float4 row pitch (49 % 8 == 1 -> bank-balanced, no XOR)
#define LOG2E 1.442695040888963f

// align_corners grid: f32 coords exactly as _resize_ac (arange(f32) * (f32(in-1)/f32(out-1))).
__device__ __forceinline__ void ac_idx(int o, int inN, float sc, int& i0, int& i1, float& w) {
#pragma clang fp contract(off)
    float s = (float)o * sc;
    float f = floorf(s);
    i0 = (int)f;
    i1 = min(i0 + 1, inN - 1);
    w = s - f;
}

// Fused kernel: one block per 4x8 pixel tile (416 blocks -> all CUs, ~2 blocks/CU).
// Stages the 44x48 union ray-window in LDS (bit-exact k_down math), 16 slice-threads
// per pixel do the sharp softmax + soft-argmax. Row pitch 49 -> ds offset immediates.
__global__ __launch_bounds__(512, 4) void k_fused(const float* __restrict__ R,
                                                  const float* __restrict__ X,
                                                  const int* __restrict__ prog,
                                                  float* __restrict__ xn,
                                                  float* __restrict__ yn) {
#pragma clang fp contract(off)
    __shared__ float4 tile[TROW * PITCH];
    __shared__ float4 dirs[32];
    __shared__ float smax_l[8][32];
    __shared__ float ssum_l[8][32][3];
    __shared__ float Tsh;

    int t = (int)threadIdx.x;
    int lane = t & 63;
    int wv = t >> 6;
    int blk = (int)blockIdx.x;
    int by = blk / NBX, bx = blk - by * NBX;
    int ph0 = by * TH, pw0 = bx * TW;
    int srow_min = min(max(ph0 - KH, 0), HS - 1 - 2 * KH);
    int scol_min = min(max(pw0 - KH, 0), WS - 1 - 2 * KH);

    // ---- stage ray tile (bit-exact f32 resize of R, mul/mul/add, no FMA) ----
    for (int e = t; e < TROW * TCOL; e += 512) {
        int i = e / TCOL, j = e - i * TCOL;
        int g = srow_min + i, cg = scol_min + j;
        if (g < HS && cg < WS) {
            int y0, y1, x0, x1; float wy, wx;
            ac_idx(g, HF, 127.0f / 63.0f, y0, y1, wy);
            ac_idx(cg, WF, 415.0f / 207.0f, x0, x1, wx);
            float omwy = 1.0f - wy, omwx = 1.0f - wx;
            float r[3];
#pragma unroll
            for (int c = 0; c < 3; ++c) {
                const float* p = R + c * (HF * WF);
                float v00 = p[y0 * WF + x0], v10 = p[y1 * WF + x0];
                float v01 = p[y0 * WF + x1], v11 = p[y1 * WF + x1];
                float a0 = v00 * omwy; float b0 = v10 * wy; float t0 = a0 + b0;
                float a1 = v01 * omwy; float b1 = v11 * wy; float t1 = a1 + b1;
                float c0 = t0 * omwx; float c1 = t1 * wx;
                r[c] = c0 + c1;
            }
            tile[i * PITCH + j] = make_float4(r[0], r[1], r[2], 0.0f);
        }
    }
    // ---- directions for the 32 tile pixels (bit-exact resize of X + normalize) ----
    if (t < 32) {
        int py = t >> 3, px = t & 7;
        int h = ph0 + py, w = pw0 + px;
        int y0, y1, x0, x1; float wy, wx;
        ac_idx(h, HF, 127.0f / 63.0f, y0, y1, wy);
        ac_idx(w, WF, 415.0f / 207.0f, x0, x1, wx);
        float omwy = 1.0f - wy, omwx = 1.0f - wx;
        float d[3];
#pragma unroll
        for (int c = 0; c < 3; ++c) {
            const float* q = X + c * (HF * WF);
            float u00 = q[y0 * WF + x0], u10 = q[y1 * WF + x0];
            float u01 = q[y0 * WF + x1], u11 = q[y1 * WF + x1];
            float e0 = u00 * omwy; float f0 = u10 * wy; float s0 = e0 + f0;
            float e1 = u01 * omwy; float f1 = u11 * wy; float s1 = e1 + f1;
            float g0 = s0 * omwx; float g1 = s1 * wx;
            d[c] = g0 + g1;
        }
        float q0 = d[0] * d[0]; float q1 = d[1] * d[1]; float q2 = d[2] * d[2];
        float ssq = (q0 + q1) + q2;
        float nrm = (float)sqrt((double)ssq);   // correctly-rounded f32 sqrt
        dirs[t] = make_float4(d[0] / nrm, d[1] / nrm, d[2] / nrm, 0.0f);
    }
    if (t == 0) {
        double T64 = fmax(1e-8, 1e-4 / exp(0.1 * (double)prog[0]));
        Tsh = (float)T64;   // same bits as np.float32(max(1e-8, 1e-4/exp(...)))
    }
    __syncthreads();

    // ---- per-thread setup: pixel p (0..31), slice s (0..15); wave holds s=2w,2w+1 ----
    int p = t & 31, s = t >> 5;
    int py = p >> 3, px = p & 7;
    int h = ph0 + py, w = pw0 + px;
    int srow = min(max(h - KH, 0), HS - 1 - 2 * KH);
    int scol = min(max(w - KH, 0), WS - 1 - 2 * KH);
    int I0 = srow - srow_min;          // 0..3
    int J0 = scol - scol_min;          // 0..7
    float4 dv = dirs[p];
    float d0 = dv.x, d1 = dv.y, d2 = dv.z;
    float Tf = Tsh;

    // ---- pass 1: rows r = s + 16q (q=0..2; q=2 iff s<=8); bit-exact logits,
    //      running max m, superset bitmask (bit = q*41+c, compile-time) ----
    float m = -INFINITY;
    unsigned mask[4] = {0u, 0u, 0u, 0u};
#pragma unroll
    for (int q = 0; q < 3; ++q) {
        bool rv = (q < 2) || (s <= 8);
        if (rv) {
            int I = I0 + s + 16 * q;
            int base = I * PITCH + J0;
#pragma unroll
            for (int c = 0; c < KS; ++c) {
                float4 v = tile[base + c];       // ds_read_b128 offset:16*c
                float p0 = d0 * v.x; float p1 = d1 * v.y; float p2 = d2 * v.z;
                float l = (p0 + p1) + p2;
                const int bit = q * KS + c;      // compile-time
                bool f = l > (m - 0.004f);
                mask[bit >> 5] |= f ? (1u << (bit & 31)) : 0u;
                m = fmaxf(m, l);
            }
        }
    }

    // ---- max reduce: slice pair within wave, then 8 waves via LDS ----
    m = fmaxf(m, __shfl_xor(m, 32));
    if (lane < 32) smax_l[wv][lane] = m;
    __syncthreads();
    float mf = smax_l[0][p];
#pragma unroll
    for (int w2 = 1; w2 < 8; ++w2) mf = fmaxf(mf, smax_l[w2][p]);

    float zm = mf / Tf;                // monotone div: == ref's max-of-(l/T)
    float thresh = mf - 0.004f;        // below: z-zm < -108 -> f32 weight exactly 0

    // ---- pass 2: revisit flagged elements only; exact IEEE div + exp2 ----
    float se = 0.f, sr = 0.f, sc = 0.f;
#pragma unroll
    for (int u = 0; u < 4; ++u) {
        unsigned w8 = mask[u];
        while (w8) {
            int b = __ffs(w8) - 1;
            w8 &= w8 - 1;
            int bit = u * 32 + b;
            int q = (bit * 25) >> 10;  // exact floor(bit/41) for bit<256
            int c = bit - q * KS;
            int r = s + 16 * q;
            int I = I0 + r;
            float4 v = tile[I * PITCH + J0 + c];
            float p0 = d0 * v.x; float p1 = d1 * v.y; float p2 = d2 * v.z;
            float l = (p0 + p1) + p2;
            if (l > thresh) {
                float z = l / Tf;      // bit-identical to ref's logits/T
                float e2 = __builtin_amdgcn_exp2f((z - zm) * LOG2E);
                se += e2;
                sr += e2 * (float)(srow + r);
                sc += e2 * (float)(scol + c);
            }
        }
    }
    se += __shfl_xor(se, 32);
    sr += __shfl_xor(sr, 32);
    sc += __shfl_xor(sc, 32);
    if (lane < 32) { ssum_l[wv][lane][0] = se; ssum_l[wv][lane][1] = sr; ssum_l[wv][lane][2] = sc; }
    __syncthreads();
    if (t < 32) {
        float SE = 0.f, SR = 0.f, SC = 0.f;
#pragma unroll
        for (int w2 = 0; w2 < 8; ++w2) {
            SE += ssum_l[w2][t][0];
            SR += ssum_l[w2][t][1];
            SC += ssum_l[w2][t][2];
        }
        int pix = (ph0 + (t >> 3)) * WS + (pw0 + (t & 7));
        double ix = (double)SR / (double)SE, iy = (double)SC / (double)SE;
        xn[pix] = (float)(2.0 * ix / (double)(HS - 1) - 1.0);
        yn[pix] = (float)(2.0 * iy / (double)(WS - 1) - 1.0);
    }
}

// Bilinear upsample (align_corners) of (Yn, Xn) to full res, interleaved channels.
__global__ void k_up(const float* __restrict__ xn, const float* __restrict__ yn,
                     float* __restrict__ out) {
#pragma clang fp contract(off)
    int i = blockIdx.x * blockDim.x + threadIdx.x;
    if (i >= HF * WF) return;
    int hh = i / WF, ww = i - hh * WF;
    int y0, y1, x0, x1; float wy, wx;
    ac_idx(hh, HS, 63.0f / 127.0f, y0, y1, wy);
    ac_idx(ww, WS, 207.0f / 415.0f, x0, x1, wx);
    float omwy = 1.0f - wy, omwx = 1.0f - wx;
    float a0, b0, t0, t1;
    a0 = xn[y0 * WS + x0] * omwy; b0 = xn[y1 * WS + x0] * wy; t0 = a0 + b0;
    a0 = xn[y0 * WS + x1] * omwy; b0 = xn[y1 * WS + x1] * wy; t1 = a0 + b0;
    float bx = t0 * omwx + t1 * wx;     // Xn upsampled
    a0 = yn[y0 * WS + x0] * omwy; b0 = yn[y1 * WS + x0] * wy; t0 = a0 + b0;
    a0 = yn[y0 * WS + x1] * omwy; b0 = yn[y1 * WS + x1] * wy; t1 = a0 + b0;
    float ay = t0 * omwx + t1 * wx;     // Yn upsampled
    out[2 * i]     = ay;
    out[2 * i + 1] = bx;
}

extern "C" void kernel_launch(void* const* d_in, const int* in_sizes, int n_in,
                              void* d_out, int out_size, void* d_ws, size_t ws_size,
                              hipStream_t stream) {
    const float* R = (const float*)d_in[0];
    const float* X = (const float*)d_in[1];
    const int* prog = (const int*)d_in[2];
    float* xn = (float*)d_ws;        // NS
    float* yn = xn + NS;             // NS
    float* out = (float*)d_out;

    k_fused<<<NBLK, 512, 0, stream>>>(R, X, prog, xn, yn);
    k_up<<<(HF * WF + 255) / 256, 256, 0, stream>>>(xn, yn, out);
}